// Round 10
// baseline (174.264 us; speedup 1.0000x reference)
//
#include <hip/hip_runtime.h>
#include <math.h>

// Problem constants (16 x 1 x 1024 x 1024 fp32 pred/mask -> scalar fp32 loss)
#define BATCH 16
#define H 1024
#define W 1024
#define TILE_W 128
#define TILE_H 64
#define TX (W / TILE_W)              // 8
#define TY (H / TILE_H)              // 16
#define NTILES (TX * TY)             // 128 tiles per batch image
// Halo: rows 64+32=96, cols 128+32=160. SAT = inclusive 2D prefix over halo.
#define RDIM 96
#define CDIM 160
#define SCOLS 161  // 161 % 32 == 1 -> scan lookups max 2-way/bank (free)
#define SEGR 40    // row-scan segment: 4 threads per 160-col line
#define SEGC 48    // col-scan segment: 2 threads per 96-row line

// d_ws: part[(c*BATCH + b)*NTILES + tile], c in [0,5) -- 40 KB. NO atomics
// (R4: contended atomicAdds serialized the GPU at ~115 atomics/us).
//
// Shape rationale (R9 post-mortem): TILE=64 plateaued at ~62us across three
// scheduling attempts (VALU 56%, occ 65%, nothing saturated) -> per-tile fixed
// cost (2 barriers, 2 scans, halo tax 2.25 cells/px, block overhead) is the
// residual. 128x64 tile: halo tax 1.88/px (-17% scan work), barriers/px and
// block count halved, phase-3 stretches 2x longer. LDS 62KB -> 2 blocks/CU;
// R7 proved residency isn't the lever, per-block efficiency is.

// DPP wave64 sum: lane 63 holds the full sum afterwards (VALU pipe, no LDS).
__device__ __forceinline__ float wave_sum_dpp(float x) {
    int t;
    t = __builtin_amdgcn_update_dpp(0, __float_as_int(x), 0x111, 0xf, 0xf, true); // row_shr:1
    x += __int_as_float(t);
    t = __builtin_amdgcn_update_dpp(0, __float_as_int(x), 0x112, 0xf, 0xf, true); // row_shr:2
    x += __int_as_float(t);
    t = __builtin_amdgcn_update_dpp(0, __float_as_int(x), 0x114, 0xf, 0xf, true); // row_shr:4
    x += __int_as_float(t);
    t = __builtin_amdgcn_update_dpp(0, __float_as_int(x), 0x118, 0xf, 0xf, true); // row_shr:8
    x += __int_as_float(t);
    t = __builtin_amdgcn_update_dpp(0, __float_as_int(x), 0x142, 0xf, 0xf, true); // row_bcast:15
    x += __int_as_float(t);
    t = __builtin_amdgcn_update_dpp(0, __float_as_int(x), 0x143, 0xf, 0xf, true); // row_bcast:31
    x += __int_as_float(t);
    return x;  // valid in lane 63
}

__global__ __launch_bounds__(512, 4)   // 4 waves/EU -> 128-VGPR budget for the scan chains
void adaptive_loss_main(const float* __restrict__ pred,
                        const float* __restrict__ mask,
                        float* __restrict__ part) {
    __shared__ float sat[RDIM * SCOLS];   // 96*161*4 = 61824 B
    __shared__ float red[8][5];

    const int tid = threadIdx.x;
    const int b   = blockIdx.z;
    const int ty0 = blockIdx.y * TILE_H;
    const int tx0 = blockIdx.x * TILE_W;
    const float* mimg = mask + (size_t)b * H * W;
    const float* pimg = pred + (size_t)b * H * W;

    // ---- Fused phase 0+1: row scan. 4 threads per halo row (96 rows, tid<384),
    //      10x float4 straight from global, prefix in registers, shfl-combine
    //      the 4 segment totals, write row-scanned values to LDS once. ----
    if (tid < 4 * RDIM) {
        const int row = tid >> 2, seg = tid & 3;
        const int gy  = ty0 - 16 + row;
        const int gx0 = tx0 - 16 + seg * SEGR;
        const bool rowok = (gy >= 0) && (gy < H);
        const float* rp = mimg + (size_t)gy * W;

        float v[SEGR];
        #pragma unroll
        for (int j = 0; j < SEGR / 4; ++j) {
            int gx = gx0 + 4 * j;                  // 16B-aligned; chunk fully in or out
            float4 t;
            if (rowok && gx >= 0 && gx < W) t = *(const float4*)(rp + gx);
            else                            t = make_float4(0.f, 0.f, 0.f, 0.f);
            v[4 * j + 0] = t.x; v[4 * j + 1] = t.y;
            v[4 * j + 2] = t.z; v[4 * j + 3] = t.w;
        }
        #pragma unroll
        for (int i = 1; i < SEGR; ++i) v[i] += v[i - 1];
        float tot = v[SEGR - 1];
        float inc = tot;
        float t1 = __shfl_up(inc, 1); if (seg >= 1) inc += t1;
        float t2 = __shfl_up(inc, 2); if (seg >= 2) inc += t2;
        const float off = inc - tot;               // exclusive prefix of segment totals
        const int base = row * SCOLS + seg * SEGR;
        #pragma unroll
        for (int i = 0; i < SEGR; ++i) sat[base + i] = v[i] + off;
    }
    __syncthreads();

    // ---- Prefetch phase-3 operands (4 groups: 2 y-groups x 2 x-halves) into
    //      the col-scan latency window. 16-lane x-mapping keeps banks 2-way. ----
    float4 m4[4], p4[4];
    #pragma unroll
    for (int g = 0; g < 4; ++g) {
        const int yi = g >> 1, xh = g & 1;
        int y  = (tid >> 4) + 32 * yi;                    // 0..63
        int x4 = ((tid & 15) << 2) + 64 * xh;             // 0..124
        size_t off = (size_t)(ty0 + y) * W + (tx0 + x4);
        m4[g] = *(const float4*)(mimg + off);
        p4[g] = *(const float4*)(pimg + off);
    }

    // ---- Phase 2: col scan. 2 threads per column (160 cols, tid<320),
    //      48 strided reads (2-way banks), register chain, 1-step shfl
    //      combine, write back. ----
    if (tid < 2 * CDIM) {
        const int col = tid >> 1, seg = tid & 1;
        const int base = (seg * SEGC) * SCOLS + col;
        float v[SEGC];
        #pragma unroll
        for (int i = 0; i < SEGC; ++i) v[i] = sat[base + i * SCOLS];
        #pragma unroll
        for (int i = 1; i < SEGC; ++i) v[i] += v[i - 1];
        float tot = v[SEGC - 1];
        float inc = tot;
        float t1 = __shfl_up(inc, 1); if (seg >= 1) inc += t1;
        const float off = inc - tot;
        #pragma unroll
        for (int i = 0; i < SEGC; ++i) sat[base + i * SCOLS] = v[i] + off;
    }
    __syncthreads();

    // ---- Phase 3: per-pixel fused compute, 16 px/thread (4 groups x 4 q).
    //      Biased bases make all corner offsets compile-time ds_read2 imms. ----
    float s_w = 0.0f, s_wb = 0.0f, s_in = 0.0f, s_un = 0.0f, s_mae = 0.0f;

    __builtin_amdgcn_s_setprio(1);
    #pragma unroll
    for (int g = 0; g < 4; ++g) {
        const int yi = g >> 1, xh = g & 1;
        const int rc  = (tid >> 4) + 32 * yi + 16;          // halo row
        const int x0c = ((tid & 15) << 2) + 64 * xh + 16;   // halo col of q=0

        float w[4] = {0.f, 0.f, 0.f, 0.f};

        #pragma unroll
        for (int j = 0; j < 3; ++j) {
            constexpr int PP[3] = {1, 7, 15};
            constexpr float INV[3] = {1.0f / 9.0f, 1.0f / 225.0f, 1.0f / 961.0f};
            const int p = PP[j];
            const int bt = (rc + p) * SCOLS + x0c - 16;      // top row (r2), biased
            const int bb = (rc - p - 1) * SCOLS + x0c - 16;  // bottom row (r1)
            #pragma unroll
            for (int q = 0; q < 4; ++q) {
                float s = sat[bt + (16 + p + q)] - sat[bb + (16 + p + q)]
                        - sat[bt + (15 - p + q)] + sat[bb + (15 - p + q)];
                w[q] += fabsf(s * INV[j] - (&m4[g].x)[q]);
            }
        }

        #pragma unroll
        for (int q = 0; q < 4; ++q) {
            float m  = (&m4[g].x)[q];
            float pr = (&p4[g].x)[q];
            float weit = 1.0f + 5.0f * w[q];
            float t    = __expf(-fabsf(pr));                 // shared by bce & sigmoid
            float bce  = fmaxf(pr, 0.0f) - pr * m + __logf(1.0f + t);
            float u    = __builtin_amdgcn_rcpf(1.0f + t);    // 1/(1+e^-|pr|)
            float sig  = (pr >= 0.0f) ? u : 1.0f - u;

            s_w   += weit;
            s_wb  += weit * bce;
            s_in  += sig * m * weit;
            s_un  += (sig + m) * weit;
            s_mae += fabsf(sig - m);
        }
    }
    __builtin_amdgcn_s_setprio(0);

    // ---- Phase 4: DPP wave reduction (VALU pipe), cross-wave via red[],
    //      5 plain stores to unique addresses. ----
    s_w   = wave_sum_dpp(s_w);
    s_wb  = wave_sum_dpp(s_wb);
    s_in  = wave_sum_dpp(s_in);
    s_un  = wave_sum_dpp(s_un);
    s_mae = wave_sum_dpp(s_mae);

    int wave = tid >> 6, lane = tid & 63;
    if (lane == 63) {
        red[wave][0] = s_w;  red[wave][1] = s_wb; red[wave][2] = s_in;
        red[wave][3] = s_un; red[wave][4] = s_mae;
    }
    __syncthreads();
    if (tid < 5) {
        float r = 0.0f;
        #pragma unroll
        for (int wv = 0; wv < 8; ++wv) r += red[wv][tid];
        const int tile = blockIdx.y * TX + blockIdx.x;
        part[((size_t)tid * BATCH + b) * NTILES + tile] = r;
    }
}

// Finalize: one block, 1024 threads. Wave w reduces batch w (128 tiles, 2 per
// lane, coalesced comp-major loads), shuffle-reduce, thread 0 scalar epilogue.
__global__ __launch_bounds__(1024)
void adaptive_loss_finalize(const float* __restrict__ part,
                            float* __restrict__ out) {
    __shared__ float sums[BATCH][5];
    const int wv   = threadIdx.x >> 6;   // 0..15 == batch
    const int lane = threadIdx.x & 63;

    float v[5];
    #pragma unroll
    for (int c = 0; c < 5; ++c) {
        float s = 0.0f;
        #pragma unroll
        for (int r = 0; r < NTILES / 64; ++r)
            s += part[((size_t)c * BATCH + wv) * NTILES + r * 64 + lane];
        v[c] = s;
    }
    #pragma unroll
    for (int off = 32; off > 0; off >>= 1) {
        #pragma unroll
        for (int c = 0; c < 5; ++c) v[c] += __shfl_down(v[c], off);
    }
    if (lane == 0) {
        #pragma unroll
        for (int c = 0; c < 5; ++c) sums[wv][c] = v[c];
    }
    __syncthreads();

    if (threadIdx.x == 0) {
        float smae = 0.0f;
        for (int b = 0; b < BATCH; ++b) smae += sums[b][4];
        float mae = smae / (float)((size_t)BATCH * H * W);
        float tot = 0.0f;
        for (int b = 0; b < BATCH; ++b) {
            float Sw  = sums[b][0];
            float Swb = sums[b][1];
            float Si  = sums[b][2];
            float Su  = sums[b][3];
            float wbce = Swb / Sw;
            float wiou = 1.0f - (Si + 1.0f) / (Su - Si + 1.0f);
            float wmae = mae * Sw / (Sw - (float)(H * W));
            tot += 0.7f * (wbce + wiou + wmae);
        }
        out[0] = tot / (float)BATCH;
    }
}

extern "C" void kernel_launch(void* const* d_in, const int* in_sizes, int n_in,
                              void* d_out, int out_size, void* d_ws, size_t ws_size,
                              hipStream_t stream) {
    const float* pred = (const float*)d_in[0];
    const float* mask = (const float*)d_in[1];
    float* part = (float*)d_ws;   // 5 * BATCH * NTILES floats = 40 KB

    dim3 grid(TX, TY, BATCH);
    adaptive_loss_main<<<grid, 512, 0, stream>>>(pred, mask, part);
    adaptive_loss_finalize<<<1, 1024, 0, stream>>>(part, (float*)d_out);
}